// Round 6
// baseline (111.896 us; speedup 1.0000x reference)
//
#include <hip/hip_runtime.h>
#include <hip/hip_bf16.h>

#define EMB 1024
#define HS 64
#define SEQ 4096

using bf16x8 = __attribute__((ext_vector_type(8))) __bf16;
using f32x4  = __attribute__((ext_vector_type(4))) float;

__device__ __forceinline__ ushort f2b(float f) {
    unsigned x = __float_as_uint(f);
    return (ushort)((x + 0x7fffu + ((x >> 16) & 1u)) >> 16);
}

// ---------------- Kernel A: Wq|Wk|Wv fp32 -> bf16 concat [192][1024] ----------------
__global__ void cvt_w(const float* __restrict__ wq, const float* __restrict__ wk,
                      const float* __restrict__ wv, ushort* __restrict__ wcat) {
    int i = blockIdx.x * 256 + threadIdx.x;
    const int n = HS * EMB;  // 65536
    if (i >= 3 * n) return;
    float f;
    if (i < n)          f = wq[i];
    else if (i < 2 * n) f = wk[i - n];
    else                f = wv[i - 2 * n];
    wcat[i] = f2b(f);
}

// ---------------- Kernel B: QKV projection (validated R1) ---------------------------
__global__ __launch_bounds__(1024) void qkv_proj(
        const float* __restrict__ x, const ushort* __restrict__ wcat,
        ushort* __restrict__ qo, ushort* __restrict__ ko, ushort* __restrict__ vo) {
    __shared__ ushort Xs[64][72];
    __shared__ ushort Ws[192][72];
    const int t = threadIdx.x;
    const int lane = t & 63, wid = t >> 6;
    const int g = lane >> 4, c = lane & 15;
    const int strip = wid >> 2, colq = wid & 3;
    const int row0 = blockIdx.x * 64;

    f32x4 acc[3];
#pragma unroll
    for (int i = 0; i < 3; ++i) acc[i] = f32x4{0.f, 0.f, 0.f, 0.f};

    for (int kc = 0; kc < EMB; kc += 64) {
        __syncthreads();
        {
            int e = t * 4, r = e >> 6, cc = e & 63;
            float4 v = *reinterpret_cast<const float4*>(&x[(row0 + r) * EMB + kc + cc]);
            ushort4 u;
            u.x = f2b(v.x); u.y = f2b(v.y); u.z = f2b(v.z); u.w = f2b(v.w);
            *reinterpret_cast<ushort4*>(&Xs[r][cc]) = u;
        }
#pragma unroll
        for (int i = 0; i < 3; ++i) {
            int e = (i * 1024 + t) * 4, r = e >> 6, cc = e & 63;
            *reinterpret_cast<ushort4*>(&Ws[r][cc]) =
                *reinterpret_cast<const ushort4*>(&wcat[r * EMB + kc + cc]);
        }
        __syncthreads();
#pragma unroll
        for (int kk = 0; kk < 2; ++kk) {
            bf16x8 a = *reinterpret_cast<const bf16x8*>(&Xs[strip * 16 + c][kk * 32 + 8 * g]);
#pragma unroll
            for (int nt = 0; nt < 3; ++nt) {
                bf16x8 b = *reinterpret_cast<const bf16x8*>(
                    &Ws[(colq * 3 + nt) * 16 + c][kk * 32 + 8 * g]);
                acc[nt] = __builtin_amdgcn_mfma_f32_16x16x32_bf16(a, b, acc[nt], 0, 0, 0);
            }
        }
    }

    const float qs = 0.125f * 1.44269504f;
#pragma unroll
    for (int nt = 0; nt < 3; ++nt) {
        int col = (colq * 3 + nt) * 16 + c;
        int rowb = row0 + strip * 16 + 4 * g;
        if (col < 64) {
#pragma unroll
            for (int r = 0; r < 4; ++r)
                qo[(rowb + r) * 64 + col] = f2b(acc[nt][r] * qs);
        } else if (col < 128) {
#pragma unroll
            for (int r = 0; r < 4; ++r)
                ko[(rowb + r) * 64 + (col - 64)] = f2b(acc[nt][r]);
        } else {
            int b = rowb >> 12, s0 = rowb & 4095;
            ushort4 pv;
            pv.x = f2b(acc[nt][0]); pv.y = f2b(acc[nt][1]);
            pv.z = f2b(acc[nt][2]); pv.w = f2b(acc[nt][3]);
            *reinterpret_cast<ushort4*>(&vo[(b * 64 + (col - 128)) * SEQ + s0]) = pv;
        }
    }
}

// ---------------- Kernel C: causal flash attention v5 -------------------------------
// 1024 blocks x 256 thr (4 waves). Block = 32 q-rows; each wave takes 1/4 of the
// causal KV range (equal work). NO barriers in the hot loop: K/V loaded direct to
// registers (8x global_load_dwordx4 per 32-kv chunk), double-buffered with a manual
// 2-phase unroll so next-chunk loads issue a full compute-phase before their use.
// P routed through a PER-WAVE LDS slice (within-wave dep only). Partials (acc, l)
// merged once at the end via LDS + one __syncthreads.
__global__ __launch_bounds__(256) void attn(
        const ushort* __restrict__ q, const ushort* __restrict__ k,
        const ushort* __restrict__ vt, float* __restrict__ out) {
    // smem: loop phase: P slices, wave w at [w*2048, w*2048+2048)
    //       merge phase (after syncthreads): acc[w] f32[32][64] at w*8192; l at 32768+w*128
    __shared__ __align__(16) char smem[33280];

    const int t = threadIdx.x;
    const int lane = t & 63, w = t >> 6;
    const int g = lane >> 4, c = lane & 15;

    const int bid = blockIdx.x;
    const int batch = bid & 7;
    const int qt = 127 - (bid >> 3);       // descending work order
    const int q0 = qt * 32;
    const int nch = qt + 1;                // causal range in 32-kv chunks
    const int c0 = (w * nch) >> 2, c1 = ((w + 1) * nch) >> 2;

    const ushort* qb = q  + (size_t)batch * SEQ * 64;
    const ushort* kb = k  + (size_t)batch * SEQ * 64;
    const ushort* vb = vt + (size_t)batch * 64 * SEQ;

    // Q fragments (resident): 32 rows = 2 strips of 16
    bf16x8 qa[2][2];
#pragma unroll
    for (int ss = 0; ss < 2; ++ss)
#pragma unroll
        for (int kk = 0; kk < 2; ++kk)
            qa[ss][kk] = *reinterpret_cast<const bf16x8*>(
                &qb[(q0 + ss * 16 + c) * 64 + kk * 32 + 8 * g]);

    f32x4 accO[2][4];
#pragma unroll
    for (int ss = 0; ss < 2; ++ss)
#pragma unroll
        for (int nt = 0; nt < 4; ++nt) accO[ss][nt] = f32x4{0.f, 0.f, 0.f, 0.f};
    float lsum[2][4] = {{0.f, 0.f, 0.f, 0.f}, {0.f, 0.f, 0.f, 0.f}};

    char* const pslice = smem + w * 2048;
    const int pwr = (c >> 3) * 256 + g * 64 + (c & 7) * 2;  // P write base within slice

    auto loadkv = [&](bf16x8 (&kf)[2][2], bf16x8 (&vf)[4], int ch) {
        const int kv0 = ch * 32;
#pragma unroll
        for (int kt = 0; kt < 2; ++kt)
#pragma unroll
            for (int kk = 0; kk < 2; ++kk)
                kf[kt][kk] = *reinterpret_cast<const bf16x8*>(
                    &kb[(kv0 + kt * 16 + c) * 64 + kk * 32 + 8 * g]);
#pragma unroll
        for (int nt = 0; nt < 4; ++nt)
            vf[nt] = *reinterpret_cast<const bf16x8*>(
                &vb[(nt * 16 + c) * SEQ + kv0 + 8 * g]);
    };

    auto compute = [&](bf16x8 (&kf)[2][2], bf16x8 (&vf)[4], int ch) {
        f32x4 sA[2][2];
#pragma unroll
        for (int ss = 0; ss < 2; ++ss)
#pragma unroll
            for (int kt = 0; kt < 2; ++kt) sA[ss][kt] = f32x4{0.f, 0.f, 0.f, 0.f};
        __builtin_amdgcn_s_setprio(1);
#pragma unroll
        for (int kk = 0; kk < 2; ++kk)
#pragma unroll
            for (int kt = 0; kt < 2; ++kt) {
                sA[0][kt] = __builtin_amdgcn_mfma_f32_16x16x32_bf16(qa[0][kk], kf[kt][kk], sA[0][kt], 0, 0, 0);
                sA[1][kt] = __builtin_amdgcn_mfma_f32_16x16x32_bf16(qa[1][kk], kf[kt][kk], sA[1][kt], 0, 0, 0);
            }
        __builtin_amdgcn_s_setprio(0);

        if (ch == nch - 1) {   // diagonal chunk: local q = ss*16+4g+r, local kv = kt*16+c
#pragma unroll
            for (int ss = 0; ss < 2; ++ss)
#pragma unroll
                for (int kt = 0; kt < 2; ++kt)
#pragma unroll
                    for (int r = 0; r < 4; ++r)
                        if (kt * 16 + c > ss * 16 + 4 * g + r) sA[ss][kt][r] = -INFINITY;
        }

        // softmax partial (no max; scores pre-scaled by 0.125*log2e) + P -> LDS A-frag
#pragma unroll
        for (int ss = 0; ss < 2; ++ss)
#pragma unroll
            for (int kt = 0; kt < 2; ++kt)
#pragma unroll
                for (int r = 0; r < 4; ++r) {
                    float p = __builtin_amdgcn_exp2f(sA[ss][kt][r]);
                    lsum[ss][r] += p;
                    *(ushort*)(pslice + ss * 1024 + kt * 512 + r * 16 + pwr) = f2b(p);
                }

        bf16x8 pa0 = *reinterpret_cast<const bf16x8*>(pslice + lane * 16);
        bf16x8 pa1 = *reinterpret_cast<const bf16x8*>(pslice + 1024 + lane * 16);

        __builtin_amdgcn_s_setprio(1);
#pragma unroll
        for (int nt = 0; nt < 4; ++nt) {
            accO[0][nt] = __builtin_amdgcn_mfma_f32_16x16x32_bf16(pa0, vf[nt], accO[0][nt], 0, 0, 0);
            accO[1][nt] = __builtin_amdgcn_mfma_f32_16x16x32_bf16(pa1, vf[nt], accO[1][nt], 0, 0, 0);
        }
        __builtin_amdgcn_s_setprio(0);
    };

    // double-buffered free-running loop (named bufs: all reg indices compile-time)
    bf16x8 kfA[2][2], vfA[4], kfB[2][2], vfB[4];
    int ch = c0;
    if (ch < c1) {
        loadkv(kfA, vfA, ch);
        while (true) {
            loadkv(kfB, vfB, (ch + 1 < c1) ? ch + 1 : ch);
            compute(kfA, vfA, ch);
            if (++ch >= c1) break;
            loadkv(kfA, vfA, (ch + 1 < c1) ? ch + 1 : ch);
            compute(kfB, vfB, ch);
            if (++ch >= c1) break;
        }
    }

    // row-sum of l across the 16 c-lanes
#pragma unroll
    for (int off = 1; off < 16; off <<= 1)
#pragma unroll
        for (int ss = 0; ss < 2; ++ss)
#pragma unroll
            for (int r = 0; r < 4; ++r)
                lsum[ss][r] += __shfl_xor(lsum[ss][r], off, 64);

    __syncthreads();   // all waves done with their P slices; repurpose LDS for merge
#pragma unroll
    for (int ss = 0; ss < 2; ++ss)
#pragma unroll
        for (int nt = 0; nt < 4; ++nt)
#pragma unroll
            for (int r = 0; r < 4; ++r)
                *(float*)(smem + w * 8192 + (ss * 16 + 4 * g + r) * 256 + (nt * 16 + c) * 4) =
                    accO[ss][nt][r];
    if (c == 0) {
#pragma unroll
        for (int ss = 0; ss < 2; ++ss)
#pragma unroll
            for (int r = 0; r < 4; ++r)
                *(float*)(smem + 32768 + w * 128 + (ss * 16 + 4 * g + r) * 4) = lsum[ss][r];
    }
    __syncthreads();

    // combine 4 KV-split partials: out = sum(acc_w) / sum(l_w)
    float* ob = out + (size_t)batch * SEQ * 64;
    const int col = t & 63, r0 = t >> 6;
#pragma unroll
    for (int rr = 0; rr < 8; ++rr) {
        int row = rr * 4 + r0;
        float s = 0.f, l = 0.f;
#pragma unroll
        for (int w4 = 0; w4 < 4; ++w4) {
            s += *(float*)(smem + w4 * 8192 + row * 256 + col * 4);
            l += *(float*)(smem + 32768 + w4 * 128 + row * 4);
        }
        ob[(q0 + row) * 64 + col] = s / l;
    }
}

extern "C" void kernel_launch(void* const* d_in, const int* in_sizes, int n_in,
                              void* d_out, int out_size, void* d_ws, size_t ws_size,
                              hipStream_t stream) {
    const float* x  = (const float*)d_in[0];
    const float* wq = (const float*)d_in[1];
    const float* wk = (const float*)d_in[2];
    const float* wv = (const float*)d_in[3];
    float* out = (float*)d_out;

    char* ws = (char*)d_ws;
    ushort* wcat = (ushort*)ws;                              // 384 KiB
    ushort* qo   = (ushort*)(ws + 393216);                   // 4 MB
    ushort* ko   = (ushort*)(ws + 393216 + 4194304);         // 4 MB
    ushort* vo   = (ushort*)(ws + 393216 + 2 * 4194304);     // 4 MB (V^T [b][64][s])

    hipLaunchKernelGGL(cvt_w, dim3(768), dim3(256), 0, stream, wq, wk, wv, wcat);
    hipLaunchKernelGGL(qkv_proj, dim3(512), dim3(1024), 0, stream, x, wcat, qo, ko, vo);
    hipLaunchKernelGGL(attn, dim3(1024), dim3(256), 0, stream, qo, ko, vo, out);
}